// Round 2
// baseline (389.611 us; speedup 1.0000x reference)
//
#include <hip/hip_runtime.h>

#define BATCH 2
#define EDIM 192
#define NHEAD 6
#define DHEAD 32
#define HH 56
#define WW 56
#define NPIX (HH * WW)   // 3136

// ---------------- NATTEN clamped window start (matches numpy reference) ----
__device__ __forceinline__ int win_start(int i, int length, int K, int dil) {
    int NS = K >> 1;
    if (dil <= 1) {
        int s = i - NS;
        if (s < 0) s = 0;
        if (i + NS >= length) s += length - i - NS - 1;
        return s;
    }
    int ni = i - NS * dil;
    int imodd = i % dil;
    int aa = (length / dil) * dil;
    int bb = length - aa;
    int end_start = (imodd < bb) ? (length - bb + imodd - 2 * NS * dil)
                                 : (aa + imodd - K * dil);
    if (ni < 0) return imodd;
    if (i + NS * dil >= length) return end_start;
    return ni;
}

// ---------------- 1x1 conv producing pixel-major q/k/v (+ channel-major v) -
// q_pm/k_pm/v_pm: (b, n, yx, 32); k pre-scaled by 32^-0.5 (after bias).
// v_cm: (b, 192, yx) for the depthwise LePE conv.
__global__ __launch_bounds__(256) void qkv_conv_kernel(
    const float* __restrict__ x, const float* __restrict__ w,
    const float* __restrict__ bias,
    float* __restrict__ q_pm, float* __restrict__ k_pm,
    float* __restrict__ v_pm, float* __restrict__ v_cm)
{
    __shared__ float wl[32 * EDIM];
    const int b = blockIdx.z;
    const int o0 = blockIdx.y * 32;          // 32-channel group: (m, head)
    const int yx = blockIdx.x * 256 + threadIdx.x;
    for (int i = threadIdx.x; i < 32 * EDIM; i += 256)
        wl[i] = w[(size_t)(o0 + i / EDIM) * EDIM + (i % EDIM)];
    __syncthreads();
    if (yx >= NPIX) return;

    const float* xp = x + (size_t)b * EDIM * NPIX + yx;
    float acc[32];
#pragma unroll
    for (int o = 0; o < 32; ++o) acc[o] = 0.f;

    for (int c = 0; c < EDIM; c += 4) {
        const float x0 = xp[(c + 0) * NPIX];
        const float x1 = xp[(c + 1) * NPIX];
        const float x2 = xp[(c + 2) * NPIX];
        const float x3 = xp[(c + 3) * NPIX];
#pragma unroll
        for (int o = 0; o < 32; ++o) {
            const float4 wv = *reinterpret_cast<const float4*>(&wl[o * EDIM + c]);
            float a = acc[o];
            a = fmaf(x0, wv.x, a);
            a = fmaf(x1, wv.y, a);
            a = fmaf(x2, wv.z, a);
            a = fmaf(x3, wv.w, a);
            acc[o] = a;
        }
    }
#pragma unroll
    for (int o = 0; o < 32; ++o) acc[o] += bias[o0 + o];

    const int m = o0 / EDIM;                 // 0=q, 1=k, 2=v
    const int n = (o0 % EDIM) / 32;          // head
    const size_t pm_off = ((size_t)(b * NHEAD + n) * NPIX + yx) * DHEAD;
    if (m == 0) {
#pragma unroll
        for (int o = 0; o < 32; o += 4)
            *reinterpret_cast<float4*>(q_pm + pm_off + o) =
                make_float4(acc[o], acc[o + 1], acc[o + 2], acc[o + 3]);
    } else if (m == 1) {
        const float ks = 0.17677669529663687f;  // 32^-0.5
#pragma unroll
        for (int o = 0; o < 32; o += 4)
            *reinterpret_cast<float4*>(k_pm + pm_off + o) =
                make_float4(acc[o] * ks, acc[o + 1] * ks, acc[o + 2] * ks, acc[o + 3] * ks);
    } else {
#pragma unroll
        for (int o = 0; o < 32; o += 4)
            *reinterpret_cast<float4*>(v_pm + pm_off + o) =
                make_float4(acc[o], acc[o + 1], acc[o + 2], acc[o + 3]);
        float* vc = v_cm + ((size_t)b * EDIM + n * 32) * NPIX + yx;
#pragma unroll
        for (int o = 0; o < 32; ++o) vc[(size_t)o * NPIX] = acc[o];
    }
}

// ---------------- depthwise 5x5 LePE on channel-major v --------------------
__global__ __launch_bounds__(256) void lepe_kernel(
    const float* __restrict__ v_cm, const float* __restrict__ w,
    const float* __restrict__ bias, float* __restrict__ out)
{
    const int t = blockIdx.x * 256 + threadIdx.x;
    if (t >= BATCH * EDIM * NPIX) return;
    const int yx = t % NPIX;
    const int bc = t / NPIX;
    const int c = bc % EDIM;
    const int y = yx / WW, x = yx % WW;

    const float* vp = v_cm + (size_t)bc * NPIX;
    const float* wp = w + (size_t)c * 25;
    float acc = bias[c];
#pragma unroll
    for (int dy = 0; dy < 5; ++dy) {
        const int yy = y + dy - 2;
        if (yy < 0 || yy >= HH) continue;
#pragma unroll
        for (int dx = 0; dx < 5; ++dx) {
            const int xx = x + dx - 2;
            if (xx < 0 || xx >= WW) continue;
            acc = fmaf(vp[yy * WW + xx], wp[dy * 5 + dx], acc);
        }
    }
    out[t] = acc;
}

// ---------------- neighborhood attention, two-phase softmax, d-split x8 ----
// q,k,v pixel-major (b,n,yx,32). lane = (pos&7)*8 + dg, 4 d per thread.
// OUT_CM: write channel-major (b, n*32+d, yx); else pixel-major.
template<int K, int DIL, bool OUT_CM>
__global__ __launch_bounds__(256) void na2d_kernel(
    const float* __restrict__ q, const float* __restrict__ k,
    const float* __restrict__ v, float* __restrict__ out)
{
    const int t = blockIdx.x * 256 + threadIdx.x;
    const int lane = threadIdx.x & 63;
    const int dg = lane & 7;                        // d-group: 4 d each
    const int pos = (t >> 6) * 8 + (lane >> 3);     // 8 positions per wave
    const int yx = pos % NPIX;
    const int bn = pos / NPIX;
    const int y = yx / WW, x = yx % WW;
    const int ys = win_start(y, HH, K, DIL);
    const int xs = win_start(x, WW, K, DIL);

    const size_t base = (size_t)bn * NPIX * DHEAD + dg * 4;
    const float4 qr = *reinterpret_cast<const float4*>(q + base + (size_t)yx * DHEAD);

    // phase 1: all K*K scores (independent loads -> deep pipelining)
    float sc[K * K];
#pragma unroll
    for (int p = 0; p < K; ++p) {
        const int rb = (ys + p * DIL) * WW + xs;
#pragma unroll
        for (int qq = 0; qq < K; ++qq) {
            const float4 kv = *reinterpret_cast<const float4*>(
                k + base + (size_t)(rb + qq * DIL) * DHEAD);
            float d0 = fmaf(qr.x, kv.x, qr.y * kv.y);
            float d1 = fmaf(qr.z, kv.z, qr.w * kv.w);
            float dot = d0 + d1;
            dot += __shfl_xor(dot, 1);
            dot += __shfl_xor(dot, 2);
            dot += __shfl_xor(dot, 4);      // full 32-d dot in all 8 lanes
            sc[p * K + qq] = dot;
        }
    }
    // phase 2: softmax over K*K
    float m = sc[0];
#pragma unroll
    for (int j = 1; j < K * K; ++j) m = fmaxf(m, sc[j]);
    float s = 0.f;
#pragma unroll
    for (int j = 0; j < K * K; ++j) { sc[j] = __expf(sc[j] - m); s += sc[j]; }
    // phase 3: PV (independent loads again)
    float4 o = make_float4(0.f, 0.f, 0.f, 0.f);
#pragma unroll
    for (int p = 0; p < K; ++p) {
        const int rb = (ys + p * DIL) * WW + xs;
#pragma unroll
        for (int qq = 0; qq < K; ++qq) {
            const float4 vv = *reinterpret_cast<const float4*>(
                v + base + (size_t)(rb + qq * DIL) * DHEAD);
            const float wgt = sc[p * K + qq];
            o.x = fmaf(wgt, vv.x, o.x);
            o.y = fmaf(wgt, vv.y, o.y);
            o.z = fmaf(wgt, vv.z, o.z);
            o.w = fmaf(wgt, vv.w, o.w);
        }
    }
    const float inv = 1.f / s;
    o.x *= inv; o.y *= inv; o.z *= inv; o.w *= inv;
    if (OUT_CM) {
        float* op = out + (size_t)bn * DHEAD * NPIX + (size_t)(dg * 4) * NPIX + yx;
        op[0] = o.x; op[NPIX] = o.y; op[2 * NPIX] = o.z; op[3 * NPIX] = o.w;
    } else {
        *reinterpret_cast<float4*>(out + base + (size_t)yx * DHEAD) = o;
    }
}

// ---------------- final 1x1 conv on (v2_cm + lepe) -------------------------
__global__ __launch_bounds__(256) void out_conv_kernel(
    const float* __restrict__ v2, const float* __restrict__ lepe,
    const float* __restrict__ w, const float* __restrict__ bias,
    float* __restrict__ out)
{
    __shared__ float wl[32 * EDIM];
    const int b = blockIdx.z;
    const int o0 = blockIdx.y * 32;
    const int yx = blockIdx.x * 256 + threadIdx.x;
    for (int i = threadIdx.x; i < 32 * EDIM; i += 256)
        wl[i] = w[(size_t)(o0 + i / EDIM) * EDIM + (i % EDIM)];
    __syncthreads();
    if (yx >= NPIX) return;

    const float* vp = v2 + (size_t)b * EDIM * NPIX + yx;
    const float* lp = lepe + (size_t)b * EDIM * NPIX + yx;
    float acc[32];
#pragma unroll
    for (int o = 0; o < 32; ++o) acc[o] = 0.f;

    for (int c = 0; c < EDIM; c += 2) {
        const float r0 = vp[(c + 0) * NPIX] + lp[(c + 0) * NPIX];
        const float r1 = vp[(c + 1) * NPIX] + lp[(c + 1) * NPIX];
#pragma unroll
        for (int o = 0; o < 32; ++o) {
            const float2 wv = *reinterpret_cast<const float2*>(&wl[o * EDIM + c]);
            acc[o] = fmaf(r0, wv.x, acc[o]);
            acc[o] = fmaf(r1, wv.y, acc[o]);
        }
    }
    float* op = out + ((size_t)b * EDIM + o0) * NPIX + yx;
#pragma unroll
    for (int o = 0; o < 32; ++o)
        op[(size_t)o * NPIX] = acc[o] + bias[o0 + o];
}

extern "C" void kernel_launch(void* const* d_in, const int* in_sizes, int n_in,
                              void* d_out, int out_size, void* d_ws, size_t ws_size,
                              hipStream_t stream)
{
    const float* x      = (const float*)d_in[0];
    const float* qkv_w  = (const float*)d_in[1];
    const float* qkv_b  = (const float*)d_in[2];
    const float* lepe_w = (const float*)d_in[3];
    const float* lepe_b = (const float*)d_in[4];
    const float* out_w  = (const float*)d_in[5];
    const float* out_b  = (const float*)d_in[6];
    float* out = (float*)d_out;

    const size_t ESZ = (size_t)BATCH * EDIM * NPIX;   // 1,204,224 floats
    float* ws   = (float*)d_ws;
    float* q_pm = ws;              // (b,n,yx,32)
    float* k_pm = q_pm + ESZ;
    float* v_pm = k_pm + ESZ;      // dead after pass 1 -> reused as v2_cm
    float* v_cm = v_pm + ESZ;      // (b,192,yx) for LePE
    float* lepe = v_cm + ESZ;
    float* v1   = lepe + ESZ;      // pass-1 output, pixel-major
    float* v2   = v_pm;            // pass-2 output, channel-major (alias)

    // 1) qkv projection (+ bias, k scaling), pixel-major outputs
    dim3 gq((NPIX + 255) / 256, (3 * EDIM) / 32, BATCH);
    qkv_conv_kernel<<<gq, 256, 0, stream>>>(x, qkv_w, qkv_b, q_pm, k_pm, v_pm, v_cm);

    // 2) LePE depthwise 5x5
    const int lepe_threads = BATCH * EDIM * NPIX;
    lepe_kernel<<<(lepe_threads + 255) / 256, 256, 0, stream>>>(v_cm, lepe_w, lepe_b, lepe);

    // 3) na2d pass 1: K=7, dil=1, pixel-major out
    const int attn_blocks = (BATCH * NHEAD * NPIX * 8) / 256;   // 1176
    na2d_kernel<7, 1, false><<<attn_blocks, 256, 0, stream>>>(q_pm, k_pm, v_pm, v1);

    // 4) na2d pass 2: K=9, dil=6, channel-major out (into v_pm's storage)
    na2d_kernel<9, 6, true><<<attn_blocks, 256, 0, stream>>>(q_pm, k_pm, v1, v2);

    // 5) output projection on (v2 + lepe)
    dim3 go((NPIX + 255) / 256, EDIM / 32, BATCH);
    out_conv_kernel<<<go, 256, 0, stream>>>(v2, lepe, out_w, out_b, out);
}

// Round 3
// 361.591 us; speedup vs baseline: 1.0775x; 1.0775x over previous
//
#include <hip/hip_runtime.h>

#define BATCH 2
#define EDIM 192
#define NHEAD 6
#define DHEAD 32
#define HH 56
#define WW 56
#define NPIX (HH * WW)   // 3136

// ---------------- NATTEN clamped window start (matches numpy reference) ----
__device__ __forceinline__ int win_start(int i, int length, int K, int dil) {
    int NS = K >> 1;
    if (dil <= 1) {
        int s = i - NS;
        if (s < 0) s = 0;
        if (i + NS >= length) s += length - i - NS - 1;
        return s;
    }
    int ni = i - NS * dil;
    int imodd = i % dil;
    int aa = (length / dil) * dil;
    int bb = length - aa;
    int end_start = (imodd < bb) ? (length - bb + imodd - 2 * NS * dil)
                                 : (aa + imodd - K * dil);
    if (ni < 0) return imodd;
    if (i + NS * dil >= length) return end_start;
    return ni;
}

#define DOT4(a, b) ((a).x * (b).x + (a).y * (b).y + (a).z * (b).z + (a).w * (b).w)

// ---------------- 1x1 conv producing pixel-major q/k/v (+ channel-major v) -
// Weights read directly (block-uniform index -> s_load path), no LDS.
__global__ __launch_bounds__(256) void qkv_conv_kernel(
    const float* __restrict__ x, const float* __restrict__ w,
    const float* __restrict__ bias,
    float* __restrict__ q_pm, float* __restrict__ k_pm,
    float* __restrict__ v_pm, float* __restrict__ v_cm)
{
    const int b = blockIdx.z;
    const int o0 = blockIdx.y * 32;          // 32-channel group: (m, head)
    const int yx = blockIdx.x * 256 + threadIdx.x;
    if (yx >= NPIX) return;

    const float* xp = x + (size_t)b * EDIM * NPIX + yx;
    const float* wp = w + (size_t)o0 * EDIM;
    float acc[32];
#pragma unroll
    for (int o = 0; o < 32; ++o) acc[o] = 0.f;

    for (int c = 0; c < EDIM; c += 4) {
        const float x0 = xp[(c + 0) * NPIX];
        const float x1 = xp[(c + 1) * NPIX];
        const float x2 = xp[(c + 2) * NPIX];
        const float x3 = xp[(c + 3) * NPIX];
#pragma unroll
        for (int o = 0; o < 32; ++o) {
            const float4 wv = *reinterpret_cast<const float4*>(wp + o * EDIM + c);
            float a = acc[o];
            a = fmaf(x0, wv.x, a);
            a = fmaf(x1, wv.y, a);
            a = fmaf(x2, wv.z, a);
            a = fmaf(x3, wv.w, a);
            acc[o] = a;
        }
    }
#pragma unroll
    for (int o = 0; o < 32; ++o) acc[o] += bias[o0 + o];

    const int m = o0 / EDIM;                 // 0=q, 1=k, 2=v
    const int n = (o0 % EDIM) / 32;          // head
    const size_t pm_off = ((size_t)(b * NHEAD + n) * NPIX + yx) * DHEAD;
    if (m == 0) {
#pragma unroll
        for (int o = 0; o < 32; o += 4)
            *reinterpret_cast<float4*>(q_pm + pm_off + o) =
                make_float4(acc[o], acc[o + 1], acc[o + 2], acc[o + 3]);
    } else if (m == 1) {
        const float ks = 0.17677669529663687f;  // 32^-0.5
#pragma unroll
        for (int o = 0; o < 32; o += 4)
            *reinterpret_cast<float4*>(k_pm + pm_off + o) =
                make_float4(acc[o] * ks, acc[o + 1] * ks, acc[o + 2] * ks, acc[o + 3] * ks);
    } else {
#pragma unroll
        for (int o = 0; o < 32; o += 4)
            *reinterpret_cast<float4*>(v_pm + pm_off + o) =
                make_float4(acc[o], acc[o + 1], acc[o + 2], acc[o + 3]);
        float* vc = v_cm + ((size_t)b * EDIM + n * 32) * NPIX + yx;
#pragma unroll
        for (int o = 0; o < 32; ++o) vc[(size_t)o * NPIX] = acc[o];
    }
}

// ---------------- depthwise 5x5 LePE on channel-major v --------------------
__global__ __launch_bounds__(256) void lepe_kernel(
    const float* __restrict__ v_cm, const float* __restrict__ w,
    const float* __restrict__ bias, float* __restrict__ out)
{
    const int t = blockIdx.x * 256 + threadIdx.x;
    if (t >= BATCH * EDIM * NPIX) return;
    const int yx = t % NPIX;
    const int bc = t / NPIX;
    const int c = bc % EDIM;
    const int y = yx / WW, x = yx % WW;

    const float* vp = v_cm + (size_t)bc * NPIX;
    const float* wp = w + (size_t)c * 25;
    float acc = bias[c];
#pragma unroll
    for (int dy = 0; dy < 5; ++dy) {
        const int yy = y + dy - 2;
        if (yy < 0 || yy >= HH) continue;
#pragma unroll
        for (int dx = 0; dx < 5; ++dx) {
            const int xx = x + dx - 2;
            if (xx < 0 || xx >= WW) continue;
            acc = fmaf(vp[yy * WW + xx], wp[dy * 5 + dx], acc);
        }
    }
    out[t] = acc;
}

// ---------------- neighborhood attention: window-row flash-decoding --------
// 8 lanes per query: lane lr in [0,8) owns window rows {lr, lr+8} (full 32 d),
// computes a partial online softmax (m, s, o[32]); xor-tree merge at the end.
// Lane layout within wave: lane = lr*8 + qs  (8 consecutive queries per wave).
template<int K, int DIL, bool OUT_CM>
__global__ __launch_bounds__(256) void na2d_kernel(
    const float* __restrict__ q, const float* __restrict__ k,
    const float* __restrict__ v, float* __restrict__ out)
{
    const int tid  = blockIdx.x * 256 + threadIdx.x;
    const int lane = threadIdx.x & 63;
    const int qs   = lane & 7;
    const int lr   = lane >> 3;                  // window-row lane 0..7
    const int qid  = (tid >> 6) * 8 + qs;        // global query index
    const int yx = qid % NPIX;
    const int bn = qid / NPIX;
    const int y = yx / WW, x = yx % WW;
    const int ys = win_start(y, HH, K, DIL);
    const int xs = win_start(x, WW, K, DIL);

    const float* qb = q + ((size_t)bn * NPIX + yx) * DHEAD;
    const float* kb = k + (size_t)bn * NPIX * DHEAD;
    const float* vb = v + (size_t)bn * NPIX * DHEAD;

    float4 qr[8];
#pragma unroll
    for (int i = 0; i < 8; ++i)
        qr[i] = reinterpret_cast<const float4*>(qb)[i];

    float m = -3.0e38f, s = 0.f;
    float4 o[8];
#pragma unroll
    for (int i = 0; i < 8; ++i) o[i] = make_float4(0.f, 0.f, 0.f, 0.f);

    for (int r = lr; r < K; r += 8) {
        const int rowoff = (ys + r * DIL) * WW + xs;
        float sc[K];
        // phase A: scores for this row (independent float4 loads)
#pragma unroll
        for (int c = 0; c < K; ++c) {
            const float4* kp = reinterpret_cast<const float4*>(
                kb + (size_t)(rowoff + c * DIL) * DHEAD);
            float d0 = DOT4(kp[0], qr[0]) + DOT4(kp[1], qr[1]);
            float d1 = DOT4(kp[2], qr[2]) + DOT4(kp[3], qr[3]);
            float d2 = DOT4(kp[4], qr[4]) + DOT4(kp[5], qr[5]);
            float d3 = DOT4(kp[6], qr[6]) + DOT4(kp[7], qr[7]);
            sc[c] = (d0 + d1) + (d2 + d3);
        }
        // online-softmax rescale for this row
        float rm = sc[0];
#pragma unroll
        for (int c = 1; c < K; ++c) rm = fmaxf(rm, sc[c]);
        const float nm = fmaxf(m, rm);
        const float alpha = __expf(m - nm);
        s *= alpha;
#pragma unroll
        for (int i = 0; i < 8; ++i) {
            o[i].x *= alpha; o[i].y *= alpha; o[i].z *= alpha; o[i].w *= alpha;
        }
        m = nm;
        // phase B: PV accumulate
#pragma unroll
        for (int c = 0; c < K; ++c) {
            const float wgt = __expf(sc[c] - m);
            s += wgt;
            const float4* vp = reinterpret_cast<const float4*>(
                vb + (size_t)(rowoff + c * DIL) * DHEAD);
#pragma unroll
            for (int i = 0; i < 8; ++i) {
                const float4 vv = vp[i];
                o[i].x = fmaf(wgt, vv.x, o[i].x);
                o[i].y = fmaf(wgt, vv.y, o[i].y);
                o[i].z = fmaf(wgt, vv.z, o[i].z);
                o[i].w = fmaf(wgt, vv.w, o[i].w);
            }
        }
    }

    // merge the 8 row-partials (lanes lr, same query) via xor tree
#pragma unroll
    for (int off = 8; off <= 32; off <<= 1) {
        const float mo = __shfl_xor(m, off);
        const float so = __shfl_xor(s, off);
        const float nm = fmaxf(m, mo);
        const float ea = __expf(m - nm);
        const float eb = __expf(mo - nm);
        s = s * ea + so * eb;
#pragma unroll
        for (int i = 0; i < 8; ++i) {
            float4 oo;
            oo.x = __shfl_xor(o[i].x, off);
            oo.y = __shfl_xor(o[i].y, off);
            oo.z = __shfl_xor(o[i].z, off);
            oo.w = __shfl_xor(o[i].w, off);
            o[i].x = o[i].x * ea + oo.x * eb;
            o[i].y = o[i].y * ea + oo.y * eb;
            o[i].z = o[i].z * ea + oo.z * eb;
            o[i].w = o[i].w * ea + oo.w * eb;
        }
        m = nm;
    }

    if (lr == 0) {
        const float inv = 1.f / s;
        if (OUT_CM) {
            float* op = out + (size_t)bn * DHEAD * NPIX + yx;
#pragma unroll
            for (int i = 0; i < 8; ++i) {
                op[(size_t)(4 * i + 0) * NPIX] = o[i].x * inv;
                op[(size_t)(4 * i + 1) * NPIX] = o[i].y * inv;
                op[(size_t)(4 * i + 2) * NPIX] = o[i].z * inv;
                op[(size_t)(4 * i + 3) * NPIX] = o[i].w * inv;
            }
        } else {
            float4* op = reinterpret_cast<float4*>(
                out + ((size_t)bn * NPIX + yx) * DHEAD);
#pragma unroll
            for (int i = 0; i < 8; ++i)
                op[i] = make_float4(o[i].x * inv, o[i].y * inv,
                                    o[i].z * inv, o[i].w * inv);
        }
    }
}

// ---------------- final 1x1 conv on (v2_cm + lepe), no LDS -----------------
__global__ __launch_bounds__(256) void out_conv_kernel(
    const float* __restrict__ v2, const float* __restrict__ lepe,
    const float* __restrict__ w, const float* __restrict__ bias,
    float* __restrict__ out)
{
    const int b = blockIdx.z;
    const int o0 = blockIdx.y * 32;
    const int yx = blockIdx.x * 256 + threadIdx.x;
    if (yx >= NPIX) return;

    const float* vp = v2 + (size_t)b * EDIM * NPIX + yx;
    const float* lp = lepe + (size_t)b * EDIM * NPIX + yx;
    const float* wp = w + (size_t)o0 * EDIM;
    float acc[32];
#pragma unroll
    for (int o = 0; o < 32; ++o) acc[o] = 0.f;

    for (int c = 0; c < EDIM; c += 4) {
        const float r0 = vp[(c + 0) * NPIX] + lp[(c + 0) * NPIX];
        const float r1 = vp[(c + 1) * NPIX] + lp[(c + 1) * NPIX];
        const float r2 = vp[(c + 2) * NPIX] + lp[(c + 2) * NPIX];
        const float r3 = vp[(c + 3) * NPIX] + lp[(c + 3) * NPIX];
#pragma unroll
        for (int o = 0; o < 32; ++o) {
            const float4 wv = *reinterpret_cast<const float4*>(wp + o * EDIM + c);
            float a = acc[o];
            a = fmaf(r0, wv.x, a);
            a = fmaf(r1, wv.y, a);
            a = fmaf(r2, wv.z, a);
            a = fmaf(r3, wv.w, a);
            acc[o] = a;
        }
    }
    float* op = out + ((size_t)b * EDIM + o0) * NPIX + yx;
#pragma unroll
    for (int o = 0; o < 32; ++o)
        op[(size_t)o * NPIX] = acc[o] + bias[o0 + o];
}

extern "C" void kernel_launch(void* const* d_in, const int* in_sizes, int n_in,
                              void* d_out, int out_size, void* d_ws, size_t ws_size,
                              hipStream_t stream)
{
    const float* x      = (const float*)d_in[0];
    const float* qkv_w  = (const float*)d_in[1];
    const float* qkv_b  = (const float*)d_in[2];
    const float* lepe_w = (const float*)d_in[3];
    const float* lepe_b = (const float*)d_in[4];
    const float* out_w  = (const float*)d_in[5];
    const float* out_b  = (const float*)d_in[6];
    float* out = (float*)d_out;

    const size_t ESZ = (size_t)BATCH * EDIM * NPIX;   // 1,204,224 floats
    float* ws   = (float*)d_ws;
    float* q_pm = ws;              // (b,n,yx,32)
    float* k_pm = q_pm + ESZ;
    float* v_pm = k_pm + ESZ;      // dead after pass 1 -> reused as v2_cm
    float* v_cm = v_pm + ESZ;      // (b,192,yx) for LePE
    float* lepe = v_cm + ESZ;
    float* v1   = lepe + ESZ;      // pass-1 output, pixel-major
    float* v2   = v_pm;            // pass-2 output, channel-major (alias)

    // 1) qkv projection (+ bias, k scaling), pixel-major outputs
    dim3 gq((NPIX + 255) / 256, (3 * EDIM) / 32, BATCH);
    qkv_conv_kernel<<<gq, 256, 0, stream>>>(x, qkv_w, qkv_b, q_pm, k_pm, v_pm, v_cm);

    // 2) LePE depthwise 5x5
    const int lepe_threads = BATCH * EDIM * NPIX;
    lepe_kernel<<<(lepe_threads + 255) / 256, 256, 0, stream>>>(v_cm, lepe_w, lepe_b, lepe);

    // 3) na2d pass 1: K=7, dil=1, pixel-major out (8 lanes per query)
    const int attn_blocks = (BATCH * NHEAD * NPIX * 8) / 256;   // 1176
    na2d_kernel<7, 1, false><<<attn_blocks, 256, 0, stream>>>(q_pm, k_pm, v_pm, v1);

    // 4) na2d pass 2: K=9, dil=6, channel-major out (into v_pm's storage)
    na2d_kernel<9, 6, true><<<attn_blocks, 256, 0, stream>>>(q_pm, k_pm, v1, v2);

    // 5) output projection on (v2 + lepe)
    dim3 go((NPIX + 255) / 256, EDIM / 32, BATCH);
    out_conv_kernel<<<go, 256, 0, stream>>>(v2, lepe, out_w, out_b, out);
}

// Round 4
// 223.738 us; speedup vs baseline: 1.7414x; 1.6161x over previous
//
#include <hip/hip_runtime.h>

#define BATCH 2
#define EDIM 192
#define NHEAD 6
#define DHEAD 32
#define HH 56
#define WW 56
#define NPIX (HH * WW)   // 3136

// ---------------- NATTEN clamped window start (matches numpy reference) ----
__device__ __forceinline__ int win_start(int i, int length, int K, int dil) {
    int NS = K >> 1;
    if (dil <= 1) {
        int s = i - NS;
        if (s < 0) s = 0;
        if (i + NS >= length) s += length - i - NS - 1;
        return s;
    }
    int ni = i - NS * dil;
    int imodd = i % dil;
    int aa = (length / dil) * dil;
    int bb = length - aa;
    int end_start = (imodd < bb) ? (length - bb + imodd - 2 * NS * dil)
                                 : (aa + imodd - K * dil);
    if (ni < 0) return imodd;
    if (i + NS * dil >= length) return end_start;
    return ni;
}

#define DOT4(a, b) ((a).x * (b).x + (a).y * (b).y + (a).z * (b).z + (a).w * (b).w)

// ---------------- 1x1 conv producing pixel-major q/k/v (+ channel-major v) -
// LDS-staged weights (broadcast reads, conflict-free).
__global__ __launch_bounds__(256) void qkv_conv_kernel(
    const float* __restrict__ x, const float* __restrict__ w,
    const float* __restrict__ bias,
    float* __restrict__ q_pm, float* __restrict__ k_pm,
    float* __restrict__ v_pm, float* __restrict__ v_cm)
{
    __shared__ float wl[32 * EDIM];
    const int b = blockIdx.z;
    const int o0 = blockIdx.y * 32;          // 32-channel group: (m, head)
    const int yx = blockIdx.x * 256 + threadIdx.x;
    for (int i = threadIdx.x; i < 32 * EDIM; i += 256)
        wl[i] = w[(size_t)(o0 + i / EDIM) * EDIM + (i % EDIM)];
    __syncthreads();
    if (yx >= NPIX) return;

    const float* xp = x + (size_t)b * EDIM * NPIX + yx;
    float acc[32];
#pragma unroll
    for (int o = 0; o < 32; ++o) acc[o] = 0.f;

    for (int c = 0; c < EDIM; c += 4) {
        const float x0 = xp[(c + 0) * NPIX];
        const float x1 = xp[(c + 1) * NPIX];
        const float x2 = xp[(c + 2) * NPIX];
        const float x3 = xp[(c + 3) * NPIX];
#pragma unroll
        for (int o = 0; o < 32; ++o) {
            const float4 wv = *reinterpret_cast<const float4*>(&wl[o * EDIM + c]);
            float a = acc[o];
            a = fmaf(x0, wv.x, a);
            a = fmaf(x1, wv.y, a);
            a = fmaf(x2, wv.z, a);
            a = fmaf(x3, wv.w, a);
            acc[o] = a;
        }
    }
#pragma unroll
    for (int o = 0; o < 32; ++o) acc[o] += bias[o0 + o];

    const int m = o0 / EDIM;                 // 0=q, 1=k, 2=v
    const int n = (o0 % EDIM) / 32;          // head
    const size_t pm_off = ((size_t)(b * NHEAD + n) * NPIX + yx) * DHEAD;
    if (m == 0) {
#pragma unroll
        for (int o = 0; o < 32; o += 4)
            *reinterpret_cast<float4*>(q_pm + pm_off + o) =
                make_float4(acc[o], acc[o + 1], acc[o + 2], acc[o + 3]);
    } else if (m == 1) {
        const float ks = 0.17677669529663687f;  // 32^-0.5
#pragma unroll
        for (int o = 0; o < 32; o += 4)
            *reinterpret_cast<float4*>(k_pm + pm_off + o) =
                make_float4(acc[o] * ks, acc[o + 1] * ks, acc[o + 2] * ks, acc[o + 3] * ks);
    } else {
#pragma unroll
        for (int o = 0; o < 32; o += 4)
            *reinterpret_cast<float4*>(v_pm + pm_off + o) =
                make_float4(acc[o], acc[o + 1], acc[o + 2], acc[o + 3]);
        float* vc = v_cm + ((size_t)b * EDIM + n * 32) * NPIX + yx;
#pragma unroll
        for (int o = 0; o < 32; ++o) vc[(size_t)o * NPIX] = acc[o];
    }
}

// ---------------- depthwise 5x5 LePE on channel-major v --------------------
__global__ __launch_bounds__(256) void lepe_kernel(
    const float* __restrict__ v_cm, const float* __restrict__ w,
    const float* __restrict__ bias, float* __restrict__ out)
{
    const int t = blockIdx.x * 256 + threadIdx.x;
    if (t >= BATCH * EDIM * NPIX) return;
    const int yx = t % NPIX;
    const int bc = t / NPIX;
    const int c = bc % EDIM;
    const int y = yx / WW, x = yx % WW;

    const float* vp = v_cm + (size_t)bc * NPIX;
    const float* wp = w + (size_t)c * 25;
    float acc = bias[c];
#pragma unroll
    for (int dy = 0; dy < 5; ++dy) {
        const int yy = y + dy - 2;
        if (yy < 0 || yy >= HH) continue;
#pragma unroll
        for (int dx = 0; dx < 5; ++dx) {
            const int xx = x + dx - 2;
            if (xx < 0 || xx >= WW) continue;
            acc = fmaf(vp[yy * WW + xx], wp[dy * 5 + dx], acc);
        }
    }
    out[t] = acc;
}

// ---------------- neighborhood attention: coalesced d-quarter split --------
// lane = qs*8 + dg : 8 queries (consecutive yx) x 8 d-quarters (float4 each).
// Interior waves: one window element = one fully-coalesced 1KB wave load.
// Dot finished with 3 xor-shuffles in the 8-lane d-group, deferred after all
// row loads are issued. Each lane owns its 4 output floats -> no final merge.
template<int K, int DIL, bool OUT_CM>
__global__ __launch_bounds__(256) void na2d_kernel(
    const float* __restrict__ q, const float* __restrict__ k,
    const float* __restrict__ v, float* __restrict__ out)
{
    const int tid  = blockIdx.x * 256 + threadIdx.x;
    const int lane = threadIdx.x & 63;
    const int dg   = lane & 7;                  // d-quarter
    const int qs   = lane >> 3;                 // query slot in wave
    const int qid  = (tid >> 6) * 8 + qs;       // global query index
    const int yx = qid % NPIX;
    const int bn = qid / NPIX;
    const int y = yx / WW, x = yx % WW;
    const int ys = win_start(y, HH, K, DIL);
    const int xs = win_start(x, WW, K, DIL);

    const float4 qr = *reinterpret_cast<const float4*>(
        q + ((size_t)bn * NPIX + yx) * DHEAD + dg * 4);
    const float* kb = k + (size_t)bn * NPIX * DHEAD + dg * 4;
    const float* vb = v + (size_t)bn * NPIX * DHEAD + dg * 4;

    float m = -3.0e38f, s = 0.f;
    float4 o = make_float4(0.f, 0.f, 0.f, 0.f);

    for (int r = 0; r < K; ++r) {
        const int rowpix = (ys + r * DIL) * WW + xs;
        const float* krow = kb + (size_t)rowpix * DHEAD;
        const float* vrow = vb + (size_t)rowpix * DHEAD;
        float4 kbuf[K], vbuf[K];
#pragma unroll
        for (int c = 0; c < K; ++c)
            kbuf[c] = *reinterpret_cast<const float4*>(krow + c * (DIL * DHEAD));
#pragma unroll
        for (int c = 0; c < K; ++c)
            vbuf[c] = *reinterpret_cast<const float4*>(vrow + c * (DIL * DHEAD));

        float sc[K];
#pragma unroll
        for (int c = 0; c < K; ++c) {
            float d = DOT4(kbuf[c], qr);
            d += __shfl_xor(d, 1);
            d += __shfl_xor(d, 2);
            d += __shfl_xor(d, 4);    // full 32-d dot in all 8 d-lanes
            sc[c] = d;
        }
        float rm = sc[0];
#pragma unroll
        for (int c = 1; c < K; ++c) rm = fmaxf(rm, sc[c]);
        const float nm = fmaxf(m, rm);
        const float alpha = __expf(m - nm);
        s *= alpha;
        o.x *= alpha; o.y *= alpha; o.z *= alpha; o.w *= alpha;
        m = nm;
#pragma unroll
        for (int c = 0; c < K; ++c) {
            const float wgt = __expf(sc[c] - m);
            s += wgt;
            o.x = fmaf(wgt, vbuf[c].x, o.x);
            o.y = fmaf(wgt, vbuf[c].y, o.y);
            o.z = fmaf(wgt, vbuf[c].z, o.z);
            o.w = fmaf(wgt, vbuf[c].w, o.w);
        }
    }
    const float inv = 1.f / s;
    o.x *= inv; o.y *= inv; o.z *= inv; o.w *= inv;
    if (OUT_CM) {
        float* op = out + ((size_t)bn * DHEAD + dg * 4) * NPIX + yx;
        op[0] = o.x; op[NPIX] = o.y; op[2 * NPIX] = o.z; op[3 * NPIX] = o.w;
    } else {
        *reinterpret_cast<float4*>(
            out + ((size_t)bn * NPIX + yx) * DHEAD + dg * 4) = o;
    }
}

// ---------------- final 1x1 conv on (v2_cm + lepe), LDS weights ------------
__global__ __launch_bounds__(256) void out_conv_kernel(
    const float* __restrict__ v2, const float* __restrict__ lepe,
    const float* __restrict__ w, const float* __restrict__ bias,
    float* __restrict__ out)
{
    __shared__ float wl[32 * EDIM];
    const int b = blockIdx.z;
    const int o0 = blockIdx.y * 32;
    const int yx = blockIdx.x * 256 + threadIdx.x;
    for (int i = threadIdx.x; i < 32 * EDIM; i += 256)
        wl[i] = w[(size_t)(o0 + i / EDIM) * EDIM + (i % EDIM)];
    __syncthreads();
    if (yx >= NPIX) return;

    const float* vp = v2 + (size_t)b * EDIM * NPIX + yx;
    const float* lp = lepe + (size_t)b * EDIM * NPIX + yx;
    float acc[32];
#pragma unroll
    for (int o = 0; o < 32; ++o) acc[o] = 0.f;

    for (int c = 0; c < EDIM; c += 4) {
        const float r0 = vp[(c + 0) * NPIX] + lp[(c + 0) * NPIX];
        const float r1 = vp[(c + 1) * NPIX] + lp[(c + 1) * NPIX];
        const float r2 = vp[(c + 2) * NPIX] + lp[(c + 2) * NPIX];
        const float r3 = vp[(c + 3) * NPIX] + lp[(c + 3) * NPIX];
#pragma unroll
        for (int o = 0; o < 32; ++o) {
            const float4 wv = *reinterpret_cast<const float4*>(&wl[o * EDIM + c]);
            float a = acc[o];
            a = fmaf(r0, wv.x, a);
            a = fmaf(r1, wv.y, a);
            a = fmaf(r2, wv.z, a);
            a = fmaf(r3, wv.w, a);
            acc[o] = a;
        }
    }
    float* op = out + ((size_t)b * EDIM + o0) * NPIX + yx;
#pragma unroll
    for (int o = 0; o < 32; ++o)
        op[(size_t)o * NPIX] = acc[o] + bias[o0 + o];
}

extern "C" void kernel_launch(void* const* d_in, const int* in_sizes, int n_in,
                              void* d_out, int out_size, void* d_ws, size_t ws_size,
                              hipStream_t stream)
{
    const float* x      = (const float*)d_in[0];
    const float* qkv_w  = (const float*)d_in[1];
    const float* qkv_b  = (const float*)d_in[2];
    const float* lepe_w = (const float*)d_in[3];
    const float* lepe_b = (const float*)d_in[4];
    const float* out_w  = (const float*)d_in[5];
    const float* out_b  = (const float*)d_in[6];
    float* out = (float*)d_out;

    const size_t ESZ = (size_t)BATCH * EDIM * NPIX;   // 1,204,224 floats
    float* ws   = (float*)d_ws;
    float* q_pm = ws;              // (b,n,yx,32)
    float* k_pm = q_pm + ESZ;
    float* v_pm = k_pm + ESZ;      // dead after pass 1 -> reused as v2_cm
    float* v_cm = v_pm + ESZ;      // (b,192,yx) for LePE
    float* lepe = v_cm + ESZ;
    float* v1   = lepe + ESZ;      // pass-1 output, pixel-major
    float* v2   = v_pm;            // pass-2 output, channel-major (alias)

    // 1) qkv projection (+ bias, k scaling), pixel-major outputs
    dim3 gq((NPIX + 255) / 256, (3 * EDIM) / 32, BATCH);
    qkv_conv_kernel<<<gq, 256, 0, stream>>>(x, qkv_w, qkv_b, q_pm, k_pm, v_pm, v_cm);

    // 2) LePE depthwise 5x5
    const int lepe_threads = BATCH * EDIM * NPIX;
    lepe_kernel<<<(lepe_threads + 255) / 256, 256, 0, stream>>>(v_cm, lepe_w, lepe_b, lepe);

    // 3) na2d pass 1: K=7, dil=1, pixel-major out
    const int attn_blocks = (BATCH * NHEAD * NPIX * 8) / 256;   // 1176
    na2d_kernel<7, 1, false><<<attn_blocks, 256, 0, stream>>>(q_pm, k_pm, v_pm, v1);

    // 4) na2d pass 2: K=9, dil=6, channel-major out (into v_pm's storage)
    na2d_kernel<9, 6, true><<<attn_blocks, 256, 0, stream>>>(q_pm, k_pm, v1, v2);

    // 5) output projection on (v2 + lepe)
    dim3 go((NPIX + 255) / 256, EDIM / 32, BATCH);
    out_conv_kernel<<<go, 256, 0, stream>>>(v2, lepe, out_w, out_b, out);
}

// Round 5
// 137.942 us; speedup vs baseline: 2.8245x; 1.6220x over previous
//
#include <hip/hip_runtime.h>

#define BATCH 2
#define EDIM 192
#define NHEAD 6
#define DHEAD 32
#define HH 56
#define WW 56
#define NPIX (HH * WW)   // 3136

// ---------------- NATTEN clamped window start (matches numpy reference) ----
__device__ __forceinline__ int win_start(int i, int length, int K, int dil) {
    int NS = K >> 1;
    if (dil <= 1) {
        int s = i - NS;
        if (s < 0) s = 0;
        if (i + NS >= length) s += length - i - NS - 1;
        return s;
    }
    int ni = i - NS * dil;
    int imodd = i % dil;
    int aa = (length / dil) * dil;
    int bb = length - aa;
    int end_start = (imodd < bb) ? (length - bb + imodd - 2 * NS * dil)
                                 : (aa + imodd - K * dil);
    if (ni < 0) return imodd;
    if (i + NS * dil >= length) return end_start;
    return ni;
}

#define DOT4(a, b) ((a).x * (b).x + (a).y * (b).y + (a).z * (b).z + (a).w * (b).w)

// ============ conv1x1, wave-split-K structure ==============================
// block = 256 thr = 4 waves; block tile = 8 outputs x 256 pixels.
// wave w reduces channels [w*48, w*48+48); combine via LDS; fused epilogue.
// Thread = 8 outputs x 4 pixels (lane + j*64). Weights: block-uniform global
// reads (s_load path). acc[8][4] gives 32 independent FMA chains.

// ---- qkv variant: writes q_pm/k_pm/v_pm (pixel-major) + v_cm --------------
__global__ __launch_bounds__(256) void qkv_conv_kernel(
    const float* __restrict__ x, const float* __restrict__ w,
    const float* __restrict__ bias,
    float* __restrict__ q_pm, float* __restrict__ k_pm,
    float* __restrict__ v_pm, float* __restrict__ v_cm)
{
    __shared__ float red[4][8][256];
    const int b  = blockIdx.z;
    const int o0 = blockIdx.y * 8;          // 8 output channels (of 576)
    const int p0 = blockIdx.x * 256;        // 256-pixel tile
    const int wv = threadIdx.x >> 6;        // wave id 0..3
    const int lane = threadIdx.x & 63;

    int pix[4];
#pragma unroll
    for (int j = 0; j < 4; ++j) {
        int p = p0 + lane + j * 64;
        pix[j] = p < NPIX ? p : NPIX - 1;   // clamp loads; writes guarded
    }
    const float* xb = x + (size_t)b * EDIM * NPIX;
    const float* wb = w + (size_t)o0 * EDIM;

    float acc[8][4];
#pragma unroll
    for (int o = 0; o < 8; ++o)
#pragma unroll
        for (int j = 0; j < 4; ++j) acc[o][j] = 0.f;

    const int c0 = wv * 48;
    for (int c = c0; c < c0 + 48; c += 4) {
        float4 wr[8];
#pragma unroll
        for (int o = 0; o < 8; ++o)
            wr[o] = *reinterpret_cast<const float4*>(wb + o * EDIM + c);
        float xv[4][4];
#pragma unroll
        for (int i = 0; i < 4; ++i) {
            const float* xc = xb + (size_t)(c + i) * NPIX;
#pragma unroll
            for (int j = 0; j < 4; ++j) xv[i][j] = xc[pix[j]];
        }
#pragma unroll
        for (int o = 0; o < 8; ++o)
#pragma unroll
            for (int j = 0; j < 4; ++j) {
                float a = acc[o][j];
                a = fmaf(xv[0][j], wr[o].x, a);
                a = fmaf(xv[1][j], wr[o].y, a);
                a = fmaf(xv[2][j], wr[o].z, a);
                a = fmaf(xv[3][j], wr[o].w, a);
                acc[o][j] = a;
            }
    }
#pragma unroll
    for (int o = 0; o < 8; ++o)
#pragma unroll
        for (int j = 0; j < 4; ++j) red[wv][o][lane + j * 64] = acc[o][j];
    __syncthreads();

    // epilogue: thread p handles pixel p0+p, all 8 outputs
    const int p = threadIdx.x;
    const int gp = p0 + p;
    if (gp >= NPIX) return;
    float vals[8];
#pragma unroll
    for (int o = 0; o < 8; ++o)
        vals[o] = red[0][o][p] + red[1][o][p] + red[2][o][p] + red[3][o][p]
                + bias[o0 + o];

    const int m  = o0 / EDIM;               // 0=q,1=k,2=v
    const int hd = (o0 % EDIM) / DHEAD;     // head
    const int d0 = o0 % DHEAD;              // d offset within head (mult of 8)
    float* pm = (m == 0 ? q_pm : (m == 1 ? k_pm : v_pm));
    if (m == 1) {
        const float ks = 0.17677669529663687f;  // 32^-0.5
#pragma unroll
        for (int o = 0; o < 8; ++o) vals[o] *= ks;
    }
    float* dst = pm + ((size_t)(b * NHEAD + hd) * NPIX + gp) * DHEAD + d0;
    *reinterpret_cast<float4*>(dst)     = make_float4(vals[0], vals[1], vals[2], vals[3]);
    *reinterpret_cast<float4*>(dst + 4) = make_float4(vals[4], vals[5], vals[6], vals[7]);
    if (m == 2) {
        float* vc = v_cm + ((size_t)b * EDIM + hd * DHEAD + d0) * NPIX + gp;
#pragma unroll
        for (int o = 0; o < 8; ++o) vc[(size_t)o * NPIX] = vals[o];
    }
}

// ---- out variant: in = v2_cm + lepe, writes channel-major d_out -----------
__global__ __launch_bounds__(256) void out_conv_kernel(
    const float* __restrict__ v2, const float* __restrict__ lepe,
    const float* __restrict__ w, const float* __restrict__ bias,
    float* __restrict__ out)
{
    __shared__ float red[4][8][256];
    const int b  = blockIdx.z;
    const int o0 = blockIdx.y * 8;          // 8 output channels (of 192)
    const int p0 = blockIdx.x * 256;
    const int wv = threadIdx.x >> 6;
    const int lane = threadIdx.x & 63;

    int pix[4];
#pragma unroll
    for (int j = 0; j < 4; ++j) {
        int p = p0 + lane + j * 64;
        pix[j] = p < NPIX ? p : NPIX - 1;
    }
    const float* vb = v2   + (size_t)b * EDIM * NPIX;
    const float* lb = lepe + (size_t)b * EDIM * NPIX;
    const float* wb = w + (size_t)o0 * EDIM;

    float acc[8][4];
#pragma unroll
    for (int o = 0; o < 8; ++o)
#pragma unroll
        for (int j = 0; j < 4; ++j) acc[o][j] = 0.f;

    const int c0 = wv * 48;
    for (int c = c0; c < c0 + 48; c += 4) {
        float4 wr[8];
#pragma unroll
        for (int o = 0; o < 8; ++o)
            wr[o] = *reinterpret_cast<const float4*>(wb + o * EDIM + c);
        float xv[4][4];
#pragma unroll
        for (int i = 0; i < 4; ++i) {
            const float* vc = vb + (size_t)(c + i) * NPIX;
            const float* lc = lb + (size_t)(c + i) * NPIX;
#pragma unroll
            for (int j = 0; j < 4; ++j) xv[i][j] = vc[pix[j]] + lc[pix[j]];
        }
#pragma unroll
        for (int o = 0; o < 8; ++o)
#pragma unroll
            for (int j = 0; j < 4; ++j) {
                float a = acc[o][j];
                a = fmaf(xv[0][j], wr[o].x, a);
                a = fmaf(xv[1][j], wr[o].y, a);
                a = fmaf(xv[2][j], wr[o].z, a);
                a = fmaf(xv[3][j], wr[o].w, a);
                acc[o][j] = a;
            }
    }
#pragma unroll
    for (int o = 0; o < 8; ++o)
#pragma unroll
        for (int j = 0; j < 4; ++j) red[wv][o][lane + j * 64] = acc[o][j];
    __syncthreads();

    const int p = threadIdx.x;
    const int gp = p0 + p;
    if (gp >= NPIX) return;
#pragma unroll
    for (int o = 0; o < 8; ++o) {
        const float val = red[0][o][p] + red[1][o][p] + red[2][o][p] + red[3][o][p]
                        + bias[o0 + o];
        out[((size_t)b * EDIM + o0 + o) * NPIX + gp] = val;
    }
}

// ---------------- depthwise 5x5 LePE on channel-major v --------------------
__global__ __launch_bounds__(256) void lepe_kernel(
    const float* __restrict__ v_cm, const float* __restrict__ w,
    const float* __restrict__ bias, float* __restrict__ out)
{
    const int t = blockIdx.x * 256 + threadIdx.x;
    if (t >= BATCH * EDIM * NPIX) return;
    const int yx = t % NPIX;
    const int bc = t / NPIX;
    const int c = bc % EDIM;
    const int y = yx / WW, x = yx % WW;

    const float* vp = v_cm + (size_t)bc * NPIX;
    const float* wp = w + (size_t)c * 25;
    float acc = bias[c];
#pragma unroll
    for (int dy = 0; dy < 5; ++dy) {
        const int yy = y + dy - 2;
        if (yy < 0 || yy >= HH) continue;
#pragma unroll
        for (int dx = 0; dx < 5; ++dx) {
            const int xx = x + dx - 2;
            if (xx < 0 || xx >= WW) continue;
            acc = fmaf(vp[yy * WW + xx], wp[dy * 5 + dx], acc);
        }
    }
    out[t] = acc;
}

// ---------------- neighborhood attention: coalesced d-quarter split --------
// lane = qs*8 + dg : 8 queries (consecutive yx) x 8 d-quarters (float4 each).
template<int K, int DIL, bool OUT_CM>
__global__ __launch_bounds__(256) void na2d_kernel(
    const float* __restrict__ q, const float* __restrict__ k,
    const float* __restrict__ v, float* __restrict__ out)
{
    const int tid  = blockIdx.x * 256 + threadIdx.x;
    const int lane = threadIdx.x & 63;
    const int dg   = lane & 7;                  // d-quarter
    const int qs   = lane >> 3;                 // query slot in wave
    const int qid  = (tid >> 6) * 8 + qs;       // global query index
    const int yx = qid % NPIX;
    const int bn = qid / NPIX;
    const int y = yx / WW, x = yx % WW;
    const int ys = win_start(y, HH, K, DIL);
    const int xs = win_start(x, WW, K, DIL);

    const float4 qr = *reinterpret_cast<const float4*>(
        q + ((size_t)bn * NPIX + yx) * DHEAD + dg * 4);
    const float* kb = k + (size_t)bn * NPIX * DHEAD + dg * 4;
    const float* vb = v + (size_t)bn * NPIX * DHEAD + dg * 4;

    float m = -3.0e38f, s = 0.f;
    float4 o = make_float4(0.f, 0.f, 0.f, 0.f);

    for (int r = 0; r < K; ++r) {
        const int rowpix = (ys + r * DIL) * WW + xs;
        const float* krow = kb + (size_t)rowpix * DHEAD;
        const float* vrow = vb + (size_t)rowpix * DHEAD;
        float4 kbuf[K], vbuf[K];
#pragma unroll
        for (int c = 0; c < K; ++c)
            kbuf[c] = *reinterpret_cast<const float4*>(krow + c * (DIL * DHEAD));
#pragma unroll
        for (int c = 0; c < K; ++c)
            vbuf[c] = *reinterpret_cast<const float4*>(vrow + c * (DIL * DHEAD));

        float sc[K];
#pragma unroll
        for (int c = 0; c < K; ++c) {
            float d = DOT4(kbuf[c], qr);
            d += __shfl_xor(d, 1);
            d += __shfl_xor(d, 2);
            d += __shfl_xor(d, 4);    // full 32-d dot in all 8 d-lanes
            sc[c] = d;
        }
        float rm = sc[0];
#pragma unroll
        for (int c = 1; c < K; ++c) rm = fmaxf(rm, sc[c]);
        const float nm = fmaxf(m, rm);
        const float alpha = __expf(m - nm);
        s *= alpha;
        o.x *= alpha; o.y *= alpha; o.z *= alpha; o.w *= alpha;
        m = nm;
#pragma unroll
        for (int c = 0; c < K; ++c) {
            const float wgt = __expf(sc[c] - m);
            s += wgt;
            o.x = fmaf(wgt, vbuf[c].x, o.x);
            o.y = fmaf(wgt, vbuf[c].y, o.y);
            o.z = fmaf(wgt, vbuf[c].z, o.z);
            o.w = fmaf(wgt, vbuf[c].w, o.w);
        }
    }
    const float inv = 1.f / s;
    o.x *= inv; o.y *= inv; o.z *= inv; o.w *= inv;
    if (OUT_CM) {
        float* op = out + ((size_t)bn * DHEAD + dg * 4) * NPIX + yx;
        op[0] = o.x; op[NPIX] = o.y; op[2 * NPIX] = o.z; op[3 * NPIX] = o.w;
    } else {
        *reinterpret_cast<float4*>(
            out + ((size_t)bn * NPIX + yx) * DHEAD + dg * 4) = o;
    }
}

extern "C" void kernel_launch(void* const* d_in, const int* in_sizes, int n_in,
                              void* d_out, int out_size, void* d_ws, size_t ws_size,
                              hipStream_t stream)
{
    const float* x      = (const float*)d_in[0];
    const float* qkv_w  = (const float*)d_in[1];
    const float* qkv_b  = (const float*)d_in[2];
    const float* lepe_w = (const float*)d_in[3];
    const float* lepe_b = (const float*)d_in[4];
    const float* out_w  = (const float*)d_in[5];
    const float* out_b  = (const float*)d_in[6];
    float* out = (float*)d_out;

    const size_t ESZ = (size_t)BATCH * EDIM * NPIX;   // 1,204,224 floats
    float* ws   = (float*)d_ws;
    float* q_pm = ws;              // (b,n,yx,32)
    float* k_pm = q_pm + ESZ;
    float* v_pm = k_pm + ESZ;      // dead after pass 1 -> reused as v2_cm
    float* v_cm = v_pm + ESZ;      // (b,192,yx) for LePE
    float* lepe = v_cm + ESZ;
    float* v1   = lepe + ESZ;      // pass-1 output, pixel-major
    float* v2   = v_pm;            // pass-2 output, channel-major (alias)

    const int ptiles = (NPIX + 255) / 256;   // 13

    // 1) qkv projection: 8 outputs x 256 pixels per block, wave-split K
    dim3 gq(ptiles, (3 * EDIM) / 8, BATCH);  // 13 x 72 x 2
    qkv_conv_kernel<<<gq, 256, 0, stream>>>(x, qkv_w, qkv_b, q_pm, k_pm, v_pm, v_cm);

    // 2) LePE depthwise 5x5
    const int lepe_threads = BATCH * EDIM * NPIX;
    lepe_kernel<<<(lepe_threads + 255) / 256, 256, 0, stream>>>(v_cm, lepe_w, lepe_b, lepe);

    // 3) na2d pass 1: K=7, dil=1, pixel-major out
    const int attn_blocks = (BATCH * NHEAD * NPIX * 8) / 256;   // 1176
    na2d_kernel<7, 1, false><<<attn_blocks, 256, 0, stream>>>(q_pm, k_pm, v_pm, v1);

    // 4) na2d pass 2: K=9, dil=6, channel-major out (into v_pm's storage)
    na2d_kernel<9, 6, true><<<attn_blocks, 256, 0, stream>>>(q_pm, k_pm, v1, v2);

    // 5) output projection on (v2 + lepe), wave-split K
    dim3 go(ptiles, EDIM / 8, BATCH);        // 13 x 24 x 2
    out_conv_kernel<<<go, 256, 0, stream>>>(v2, lepe, out_w, out_b, out);
}

// Round 6
// 132.234 us; speedup vs baseline: 2.9464x; 1.0432x over previous
//
#include <hip/hip_runtime.h>

#define BATCH 2
#define EDIM 192
#define NHEAD 6
#define DHEAD 32
#define HH 56
#define WW 56
#define NPIX (HH * WW)   // 3136

// ---------------- NATTEN clamped window start (matches numpy reference) ----
__device__ __forceinline__ int win_start(int i, int length, int K, int dil) {
    int NS = K >> 1;
    if (dil <= 1) {
        int s = i - NS;
        if (s < 0) s = 0;
        if (i + NS >= length) s += length - i - NS - 1;
        return s;
    }
    int ni = i - NS * dil;
    int imodd = i % dil;
    int aa = (length / dil) * dil;
    int bb = length - aa;
    int end_start = (imodd < bb) ? (length - bb + imodd - 2 * NS * dil)
                                 : (aa + imodd - K * dil);
    if (ni < 0) return imodd;
    if (i + NS * dil >= length) return end_start;
    return ni;
}

#define DOT4(a, b) ((a).x * (b).x + (a).y * (b).y + (a).z * (b).z + (a).w * (b).w)

// ============ conv1x1, wave-split-K, L2-swizzled, dbuf'd ===================
// block = 256 thr = 4 waves; tile = 8 outputs x 256 pixels; wave w reduces
// channels [w*48, w*48+48); LDS combine + fused epilogue.
// Thread pixel set: lane*4+j  -> one dwordx4 load per channel (1KB/wave).
// blockIdx.x = output-group (fastest) so all o-blocks sharing a pixel tile
// dispatch together -> x tile stays L2-resident.

// ---- qkv variant ----------------------------------------------------------
__global__ __launch_bounds__(256) void qkv_conv_kernel(
    const float* __restrict__ x, const float* __restrict__ w,
    const float* __restrict__ bias,
    float* __restrict__ q_pm, float* __restrict__ k_pm,
    float* __restrict__ v_pm, float* __restrict__ v_cm)
{
    __shared__ float red[4][8][256];
    const int b  = blockIdx.z;
    const int o0 = blockIdx.x * 8;          // 8 output channels (of 576)
    const int p0 = blockIdx.y * 256;        // 256-pixel tile
    const int wv = threadIdx.x >> 6;        // wave id 0..3
    const int lane = threadIdx.x & 63;

    int pb = p0 + lane * 4;                 // 4 consecutive pixels per lane
    if (pb > NPIX - 4) pb = NPIX - 4;       // clamp loads; writes guarded
    const float* xb = x + (size_t)b * EDIM * NPIX + pb;
    const float* wb = w + (size_t)o0 * EDIM;

    float acc[8][4];
#pragma unroll
    for (int o = 0; o < 8; ++o)
#pragma unroll
        for (int j = 0; j < 4; ++j) acc[o][j] = 0.f;

    const int c0 = wv * 48;
    float4 xA[4], xB[4];
#pragma unroll
    for (int i = 0; i < 4; ++i)
        xA[i] = *reinterpret_cast<const float4*>(xb + (size_t)(c0 + i) * NPIX);

#define QKV_FMA(XBUF, CC)                                                     \
    {                                                                         \
        float4 wr[8];                                                         \
        _Pragma("unroll")                                                     \
        for (int o = 0; o < 8; ++o)                                           \
            wr[o] = *reinterpret_cast<const float4*>(wb + o * EDIM + (CC));   \
        _Pragma("unroll")                                                     \
        for (int o = 0; o < 8; ++o) {                                         \
            float4 a = make_float4(acc[o][0], acc[o][1], acc[o][2], acc[o][3]);\
            a.x = fmaf(XBUF[0].x, wr[o].x, a.x);                              \
            a.y = fmaf(XBUF[0].y, wr[o].x, a.y);                              \
            a.z = fmaf(XBUF[0].z, wr[o].x, a.z);                              \
            a.w = fmaf(XBUF[0].w, wr[o].x, a.w);                              \
            a.x = fmaf(XBUF[1].x, wr[o].y, a.x);                              \
            a.y = fmaf(XBUF[1].y, wr[o].y, a.y);                              \
            a.z = fmaf(XBUF[1].z, wr[o].y, a.z);                              \
            a.w = fmaf(XBUF[1].w, wr[o].y, a.w);                              \
            a.x = fmaf(XBUF[2].x, wr[o].z, a.x);                              \
            a.y = fmaf(XBUF[2].y, wr[o].z, a.y);                              \
            a.z = fmaf(XBUF[2].z, wr[o].z, a.z);                              \
            a.w = fmaf(XBUF[2].w, wr[o].z, a.w);                              \
            a.x = fmaf(XBUF[3].x, wr[o].w, a.x);                              \
            a.y = fmaf(XBUF[3].y, wr[o].w, a.y);                              \
            a.z = fmaf(XBUF[3].z, wr[o].w, a.z);                              \
            a.w = fmaf(XBUF[3].w, wr[o].w, a.w);                              \
            acc[o][0] = a.x; acc[o][1] = a.y; acc[o][2] = a.z; acc[o][3] = a.w;\
        }                                                                     \
    }

    for (int c = c0; c < c0 + 48; c += 8) {
#pragma unroll
        for (int i = 0; i < 4; ++i)
            xB[i] = *reinterpret_cast<const float4*>(xb + (size_t)(c + 4 + i) * NPIX);
        QKV_FMA(xA, c);
        if (c + 8 < c0 + 48) {
#pragma unroll
            for (int i = 0; i < 4; ++i)
                xA[i] = *reinterpret_cast<const float4*>(xb + (size_t)(c + 8 + i) * NPIX);
        }
        QKV_FMA(xB, c + 4);
    }
#undef QKV_FMA

#pragma unroll
    for (int o = 0; o < 8; ++o)
#pragma unroll
        for (int j = 0; j < 4; ++j) red[wv][o][lane * 4 + j] = acc[o][j];
    __syncthreads();

    // epilogue: thread p handles pixel p0+p, all 8 outputs
    const int p = threadIdx.x;
    const int gp = p0 + p;
    if (gp >= NPIX) return;
    float vals[8];
#pragma unroll
    for (int o = 0; o < 8; ++o)
        vals[o] = red[0][o][p] + red[1][o][p] + red[2][o][p] + red[3][o][p]
                + bias[o0 + o];

    const int m  = o0 / EDIM;               // 0=q,1=k,2=v
    const int hd = (o0 % EDIM) / DHEAD;     // head
    const int d0 = o0 % DHEAD;              // d offset within head (mult of 8)
    float* pm = (m == 0 ? q_pm : (m == 1 ? k_pm : v_pm));
    if (m == 1) {
        const float ks = 0.17677669529663687f;  // 32^-0.5
#pragma unroll
        for (int o = 0; o < 8; ++o) vals[o] *= ks;
    }
    float* dst = pm + ((size_t)(b * NHEAD + hd) * NPIX + gp) * DHEAD + d0;
    *reinterpret_cast<float4*>(dst)     = make_float4(vals[0], vals[1], vals[2], vals[3]);
    *reinterpret_cast<float4*>(dst + 4) = make_float4(vals[4], vals[5], vals[6], vals[7]);
    if (m == 2) {
        float* vc = v_cm + ((size_t)b * EDIM + hd * DHEAD + d0) * NPIX + gp;
#pragma unroll
        for (int o = 0; o < 8; ++o) vc[(size_t)o * NPIX] = vals[o];
    }
}

// ---- out variant: in = v2_cm + lepe, writes channel-major d_out -----------
__global__ __launch_bounds__(256) void out_conv_kernel(
    const float* __restrict__ v2, const float* __restrict__ lepe,
    const float* __restrict__ w, const float* __restrict__ bias,
    float* __restrict__ out)
{
    __shared__ float red[4][8][256];
    const int b  = blockIdx.z;
    const int o0 = blockIdx.x * 8;          // 8 output channels (of 192)
    const int p0 = blockIdx.y * 256;
    const int wv = threadIdx.x >> 6;
    const int lane = threadIdx.x & 63;

    int pb = p0 + lane * 4;
    if (pb > NPIX - 4) pb = NPIX - 4;
    const float* vb = v2   + (size_t)b * EDIM * NPIX + pb;
    const float* lb = lepe + (size_t)b * EDIM * NPIX + pb;
    const float* wb = w + (size_t)o0 * EDIM;

    float acc[8][4];
#pragma unroll
    for (int o = 0; o < 8; ++o)
#pragma unroll
        for (int j = 0; j < 4; ++j) acc[o][j] = 0.f;

    const int c0 = wv * 48;
    float4 vA[4], lA[4], vB[4], lB[4];
#pragma unroll
    for (int i = 0; i < 4; ++i) {
        vA[i] = *reinterpret_cast<const float4*>(vb + (size_t)(c0 + i) * NPIX);
        lA[i] = *reinterpret_cast<const float4*>(lb + (size_t)(c0 + i) * NPIX);
    }

#define OUT_FMA(VBUF, LBUF, CC)                                               \
    {                                                                         \
        float4 wr[8];                                                         \
        _Pragma("unroll")                                                     \
        for (int o = 0; o < 8; ++o)                                           \
            wr[o] = *reinterpret_cast<const float4*>(wb + o * EDIM + (CC));   \
        float4 xs[4];                                                         \
        _Pragma("unroll")                                                     \
        for (int i = 0; i < 4; ++i)                                           \
            xs[i] = make_float4(VBUF[i].x + LBUF[i].x, VBUF[i].y + LBUF[i].y, \
                                VBUF[i].z + LBUF[i].z, VBUF[i].w + LBUF[i].w);\
        _Pragma("unroll")                                                     \
        for (int o = 0; o < 8; ++o) {                                         \
            float4 a = make_float4(acc[o][0], acc[o][1], acc[o][2], acc[o][3]);\
            a.x = fmaf(xs[0].x, wr[o].x, a.x);                                \
            a.y = fmaf(xs[0].y, wr[o].x, a.y);                                \
            a.z = fmaf(xs[0].z, wr[o].x, a.z);                                \
            a.w = fmaf(xs[0].w, wr[o].x, a.w);                                \
            a.x = fmaf(xs[1].x, wr[o].y, a.x);                                \
            a.y = fmaf(xs[1].y, wr[o].y, a.y);                                \
            a.z = fmaf(xs[1].z, wr[o].y, a.z);                                \
            a.w = fmaf(xs[1].w, wr[o].y, a.w);                                \
            a.x = fmaf(xs[2].x, wr[o].z, a.x);                                \
            a.y = fmaf(xs[2].y, wr[o].z, a.y);                                \
            a.z = fmaf(xs[2].z, wr[o].z, a.z);                                \
            a.w = fmaf(xs[2].w, wr[o].z, a.w);                                \
            a.x = fmaf(xs[3].x, wr[o].w, a.x);                                \
            a.y = fmaf(xs[3].y, wr[o].w, a.y);                                \
            a.z = fmaf(xs[3].z, wr[o].w, a.z);                                \
            a.w = fmaf(xs[3].w, wr[o].w, a.w);                                \
            acc[o][0] = a.x; acc[o][1] = a.y; acc[o][2] = a.z; acc[o][3] = a.w;\
        }                                                                     \
    }

    for (int c = c0; c < c0 + 48; c += 8) {
#pragma unroll
        for (int i = 0; i < 4; ++i) {
            vB[i] = *reinterpret_cast<const float4*>(vb + (size_t)(c + 4 + i) * NPIX);
            lB[i] = *reinterpret_cast<const float4*>(lb + (size_t)(c + 4 + i) * NPIX);
        }
        OUT_FMA(vA, lA, c);
        if (c + 8 < c0 + 48) {
#pragma unroll
            for (int i = 0; i < 4; ++i) {
                vA[i] = *reinterpret_cast<const float4*>(vb + (size_t)(c + 8 + i) * NPIX);
                lA[i] = *reinterpret_cast<const float4*>(lb + (size_t)(c + 8 + i) * NPIX);
            }
        }
        OUT_FMA(vB, lB, c + 4);
    }
#undef OUT_FMA

#pragma unroll
    for (int o = 0; o < 8; ++o)
#pragma unroll
        for (int j = 0; j < 4; ++j) red[wv][o][lane * 4 + j] = acc[o][j];
    __syncthreads();

    const int p = threadIdx.x;
    const int gp = p0 + p;
    if (gp >= NPIX) return;
#pragma unroll
    for (int o = 0; o < 8; ++o) {
        const float val = red[0][o][p] + red[1][o][p] + red[2][o][p] + red[3][o][p]
                        + bias[o0 + o];
        out[((size_t)b * EDIM + o0 + o) * NPIX + gp] = val;
    }
}

// ---------------- depthwise 5x5 LePE on channel-major v --------------------
__global__ __launch_bounds__(256) void lepe_kernel(
    const float* __restrict__ v_cm, const float* __restrict__ w,
    const float* __restrict__ bias, float* __restrict__ out)
{
    const int t = blockIdx.x * 256 + threadIdx.x;
    if (t >= BATCH * EDIM * NPIX) return;
    const int yx = t % NPIX;
    const int bc = t / NPIX;
    const int c = bc % EDIM;
    const int y = yx / WW, x = yx % WW;

    const float* vp = v_cm + (size_t)bc * NPIX;
    const float* wp = w + (size_t)c * 25;
    float acc = bias[c];
#pragma unroll
    for (int dy = 0; dy < 5; ++dy) {
        const int yy = y + dy - 2;
        if (yy < 0 || yy >= HH) continue;
#pragma unroll
        for (int dx = 0; dx < 5; ++dx) {
            const int xx = x + dx - 2;
            if (xx < 0 || xx >= WW) continue;
            acc = fmaf(vp[yy * WW + xx], wp[dy * 5 + dx], acc);
        }
    }
    out[t] = acc;
}

// ---------------- neighborhood attention: coalesced d-quarter split --------
// lane = qs*8 + dg : 8 queries (consecutive yx) x 8 d-quarters (float4 each).
template<int K, int DIL, bool OUT_CM>
__global__ __launch_bounds__(256) void na2d_kernel(
    const float* __restrict__ q, const float* __restrict__ k,
    const float* __restrict__ v, float* __restrict__ out)
{
    const int tid  = blockIdx.x * 256 + threadIdx.x;
    const int lane = threadIdx.x & 63;
    const int dg   = lane & 7;                  // d-quarter
    const int qs   = lane >> 3;                 // query slot in wave
    const int qid  = (tid >> 6) * 8 + qs;       // global query index
    const int yx = qid % NPIX;
    const int bn = qid / NPIX;
    const int y = yx / WW, x = yx % WW;
    const int ys = win_start(y, HH, K, DIL);
    const int xs = win_start(x, WW, K, DIL);

    const float4 qr = *reinterpret_cast<const float4*>(
        q + ((size_t)bn * NPIX + yx) * DHEAD + dg * 4);
    const float* kb = k + (size_t)bn * NPIX * DHEAD + dg * 4;
    const float* vb = v + (size_t)bn * NPIX * DHEAD + dg * 4;

    float m = -3.0e38f, s = 0.f;
    float4 o = make_float4(0.f, 0.f, 0.f, 0.f);

    for (int r = 0; r < K; ++r) {
        const int rowpix = (ys + r * DIL) * WW + xs;
        const float* krow = kb + (size_t)rowpix * DHEAD;
        const float* vrow = vb + (size_t)rowpix * DHEAD;
        float4 kbuf[K], vbuf[K];
#pragma unroll
        for (int c = 0; c < K; ++c)
            kbuf[c] = *reinterpret_cast<const float4*>(krow + c * (DIL * DHEAD));
#pragma unroll
        for (int c = 0; c < K; ++c)
            vbuf[c] = *reinterpret_cast<const float4*>(vrow + c * (DIL * DHEAD));

        float sc[K];
#pragma unroll
        for (int c = 0; c < K; ++c) {
            float d = DOT4(kbuf[c], qr);
            d += __shfl_xor(d, 1);
            d += __shfl_xor(d, 2);
            d += __shfl_xor(d, 4);    // full 32-d dot in all 8 d-lanes
            sc[c] = d;
        }
        float rm = sc[0];
#pragma unroll
        for (int c = 1; c < K; ++c) rm = fmaxf(rm, sc[c]);
        const float nm = fmaxf(m, rm);
        const float alpha = __expf(m - nm);
        s *= alpha;
        o.x *= alpha; o.y *= alpha; o.z *= alpha; o.w *= alpha;
        m = nm;
#pragma unroll
        for (int c = 0; c < K; ++c) {
            const float wgt = __expf(sc[c] - m);
            s += wgt;
            o.x = fmaf(wgt, vbuf[c].x, o.x);
            o.y = fmaf(wgt, vbuf[c].y, o.y);
            o.z = fmaf(wgt, vbuf[c].z, o.z);
            o.w = fmaf(wgt, vbuf[c].w, o.w);
        }
    }
    const float inv = 1.f / s;
    o.x *= inv; o.y *= inv; o.z *= inv; o.w *= inv;
    if (OUT_CM) {
        float* op = out + ((size_t)bn * DHEAD + dg * 4) * NPIX + yx;
        op[0] = o.x; op[NPIX] = o.y; op[2 * NPIX] = o.z; op[3 * NPIX] = o.w;
    } else {
        *reinterpret_cast<float4*>(
            out + ((size_t)bn * NPIX + yx) * DHEAD + dg * 4) = o;
    }
}

extern "C" void kernel_launch(void* const* d_in, const int* in_sizes, int n_in,
                              void* d_out, int out_size, void* d_ws, size_t ws_size,
                              hipStream_t stream)
{
    const float* x      = (const float*)d_in[0];
    const float* qkv_w  = (const float*)d_in[1];
    const float* qkv_b  = (const float*)d_in[2];
    const float* lepe_w = (const float*)d_in[3];
    const float* lepe_b = (const float*)d_in[4];
    const float* out_w  = (const float*)d_in[5];
    const float* out_b  = (const float*)d_in[6];
    float* out = (float*)d_out;

    const size_t ESZ = (size_t)BATCH * EDIM * NPIX;   // 1,204,224 floats
    float* ws   = (float*)d_ws;
    float* q_pm = ws;              // (b,n,yx,32)
    float* k_pm = q_pm + ESZ;
    float* v_pm = k_pm + ESZ;      // dead after pass 1 -> reused as v2_cm
    float* v_cm = v_pm + ESZ;      // (b,192,yx) for LePE
    float* lepe = v_cm + ESZ;
    float* v1   = lepe + ESZ;      // pass-1 output, pixel-major
    float* v2   = v_pm;            // pass-2 output, channel-major (alias)

    const int ptiles = (NPIX + 255) / 256;   // 13

    // 1) qkv projection: o-group fastest (L2-resident x tile)
    dim3 gq((3 * EDIM) / 8, ptiles, BATCH);  // 72 x 13 x 2
    qkv_conv_kernel<<<gq, 256, 0, stream>>>(x, qkv_w, qkv_b, q_pm, k_pm, v_pm, v_cm);

    // 2) LePE depthwise 5x5
    const int lepe_threads = BATCH * EDIM * NPIX;
    lepe_kernel<<<(lepe_threads + 255) / 256, 256, 0, stream>>>(v_cm, lepe_w, lepe_b, lepe);

    // 3) na2d pass 1: K=7, dil=1, pixel-major out
    const int attn_blocks = (BATCH * NHEAD * NPIX * 8) / 256;   // 1176
    na2d_kernel<7, 1, false><<<attn_blocks, 256, 0, stream>>>(q_pm, k_pm, v_pm, v1);

    // 4) na2d pass 2: K=9, dil=6, channel-major out (into v_pm's storage)
    na2d_kernel<9, 6, true><<<attn_blocks, 256, 0, stream>>>(q_pm, k_pm, v1, v2);

    // 5) output projection on (v2 + lepe), o-group fastest
    dim3 go(EDIM / 8, ptiles, BATCH);        // 24 x 13 x 2
    out_conv_kernel<<<go, 256, 0, stream>>>(v2, lepe, out_w, out_b, out);
}